// Round 12
// baseline (116.364 us; speedup 1.0000x reference)
//
#include <hip/hip_runtime.h>
#include <cstdint>
#include <cstddef>

#define TPB  256
#define SPAN (TPB * 2)       // 512 anchors per block (2 sequential tiles)
#define NW   (TPB / 64)
#define MAXT 128             // max targets supported (T=64 here)
#define BIGC 1e18f           // far-away point box for invalid targets

// ---------------------------------------------------------------------------
// Focal-term helpers (hardware exp2/log2/rcp).
// f_bg(x) = 0.25 sigmoid(x)^2 softplus(x); f_fg = 0.75 (1-sig)^2 softplus(-x)
// f_bg4 returns RAW sum sigmoid^2 * softplus(x)/ln2 (K_BG applied once).
// ---------------------------------------------------------------------------
#define K_BG 0.17328679514f   // 0.25 * ln(2)

__device__ __forceinline__ float f_bg4(float4 v) {
    float r = 0.f;
    const float xs[4] = {v.x, v.y, v.z, v.w};
    #pragma unroll
    for (int i = 0; i < 4; ++i) {
        const float x  = xs[i];
        const float u  = x * 1.44269504089f;
        const float em = __builtin_amdgcn_exp2f(-fabsf(u));  // e^-|x|
        const float oe = 1.f + em;
        const float l2 = __builtin_amdgcn_logf(oe);          // log2(1+e^-|x|)
        const float s  = __builtin_amdgcn_rcpf(oe);          // sigmoid(|x|)
        const float sp2 = fmaxf(u, 0.f) + l2;                // softplus(x)/ln2
        const float p  = (x >= 0.f) ? s : (1.f - s);
        r = fmaf(p * p, sp2, r);
    }
    return r;
}

__device__ __forceinline__ float f_fg_minus_bg(float x) {
    const float ax = fabsf(x);
    const float em = __builtin_amdgcn_exp2f(ax * -1.44269504089f);
    const float oe = 1.f + em;
    const float l  = __builtin_amdgcn_logf(oe) * 0.69314718056f;
    const float s  = __builtin_amdgcn_rcpf(oe);
    const float sp_p = (x >= 0.f) ? (x + l) : l;
    const float sp_n = sp_p - x;
    const float p  = (x >= 0.f) ? s : (1.f - s);
    const float q  = 1.f - p;
    return 0.75f * q * q * sp_n - 0.25f * p * p * sp_p;
}

__device__ __forceinline__ void iou_step(float g_tl0, float g_tl1, float g_br0,
                                         float g_br1, float g_area_eps,
                                         const float4 ta, int tt,
                                         float& bI, float& bU, int& besti) {
    const float tl0 = fmaxf(g_tl0, ta.x);
    const float tl1 = fmaxf(g_tl1, ta.y);
    const float br0 = fminf(g_br0, ta.z);
    const float br1 = fminf(g_br1, ta.w);
    const float sz0 = fmaxf(br0 - tl0, 0.0f);
    const float sz1 = fmaxf(br1 - tl1, 0.0f);
    const float inter = sz0 * sz1;
    const float tarea = (ta.z - ta.x) * (ta.w - ta.y);
    const float uni = g_area_eps + tarea - inter;
    const bool upd = inter * bU > bI * uni;   // iou_t > iou_best, exact compare
    bI = upd ? inter : bI;
    bU = upd ? uni   : bU;
    besti = upd ? tt : besti;
}

// Verbatim round-10 hot loop: pipelined f_bg over one [256 x C4] tile,
// interleaved with IoU over the pruned active list. All state scalar.
template<int C4T>
__device__ __forceinline__ void tile_pass(const float4* __restrict__ tbase,
                                          int tid, int nact,
                                          const int* __restrict__ s_act,
                                          const float4* __restrict__ s_ta,
                                          float g_tl0, float g_tl1,
                                          float g_br0, float g_br1, float g_ae,
                                          float& raw, float& bI, float& bU,
                                          int& besti)
{
    constexpr int CH  = 5;
    constexpr int NCH = C4T / CH;          // 4 for C4=20
    float4 cur[CH];
    #pragma unroll
    for (int i = 0; i < CH; ++i) cur[i] = tbase[tid + i * TPB];
    const int cs = (nact + NCH - 1) / NCH;
    #pragma unroll
    for (int g = 0; g < NCH; ++g) {
        float4 nxt[CH];
        if (g + 1 < NCH) {
            #pragma unroll
            for (int i = 0; i < CH; ++i)
                nxt[i] = tbase[tid + ((g + 1) * CH + i) * TPB];
        }
        #pragma unroll
        for (int i = 0; i < CH; ++i) raw += f_bg4(cur[i]);
        const int te = min((g + 1) * cs, nact);
        for (int t = g * cs; t < te; ++t) {
            const int tt = s_act[t];
            iou_step(g_tl0, g_tl1, g_br0, g_br1, g_ae, s_ta[tt], tt, bI, bU, besti);
        }
        if (g + 1 < NCH) {
            #pragma unroll
            for (int i = 0; i < CH; ++i) cur[i] = nxt[i];
        }
    }
}

// ---------------------------------------------------------------------------
// Fused kernel. Per block = 512 contiguous anchors (2 sequential tiles).
// Staging + bbox-prune + compaction + corrections + reduce paid ONCE per 512.
// All per-tile state is scalar (no runtime-indexed arrays -> no scratch).
// __launch_bounds__(256,4): VGPR cap 128.  No atomics anywhere.
// ---------------------------------------------------------------------------
template<int C4T>
__global__ __launch_bounds__(TPB, 4)
void fused_kernel(const float* __restrict__ bbox_preds,  // [B,A,4]
                  const float* __restrict__ bbox_tgts,   // [B,T,4] tlbr
                  const int*   __restrict__ clas_tgts,   // [B,T]
                  const float* __restrict__ anchors,     // [A,4] cthw
                  const float* __restrict__ clas_preds,  // [B,A,C]
                  int A, int T, int C4rt,
                  float* __restrict__ np_p,   // [B*nblk]
                  float* __restrict__ bb_p,   // [B*nblk]
                  float* __restrict__ cl_p,   // [B*nblk]
                  int nblk)
{
    const int C4  = (C4T > 0) ? C4T : C4rt;
    const int b   = blockIdx.y;
    const int a0  = blockIdx.x * SPAN;
    const int tid = threadIdx.x;
    const int lane = tid & 63;
    const int wid  = tid >> 6;
    const int nA  = min(SPAN, A - a0);
    const bool in0 = (a0 + tid) < A;
    const bool in1 = (a0 + TPB + tid) < A;

    const float4* tile = reinterpret_cast<const float4*>(clas_preds)
                         + ((size_t)b * A + a0) * C4;

    // ---- stage targets into LDS ----
    __shared__ float4 s_ta[MAXT];   // tlbr (point box at BIGC if invalid)
    __shared__ int    s_cls[MAXT];
    for (int i = tid; i < T; i += TPB) {
        const float4 tg = reinterpret_cast<const float4*>(bbox_tgts)[(size_t)b * T + i];
        const int   cl = clas_tgts[(size_t)b * T + i];
        const float c0 = (tg.x + tg.z) * 0.5f, c1 = (tg.y + tg.w) * 0.5f;
        const float s0 = tg.z - tg.x,          s1 = tg.w - tg.y;
        s_ta[i] = (cl > 0) ? make_float4(c0 - s0 * 0.5f, c1 - s1 * 0.5f,
                                         c0 + s0 * 0.5f, c1 + s1 * 0.5f)
                           : make_float4(BIGC, BIGC, BIGC, BIGC);
        s_cls[i] = cl;
    }

    // ---- per-tile anchor geometry (scalars) ----
    float4 anc0 = make_float4(0.f, 0.f, 1.f, 1.f);
    float4 anc1 = make_float4(0.f, 0.f, 1.f, 1.f);
    if (in0) anc0 = reinterpret_cast<const float4*>(anchors)[a0 + tid];
    if (in1) anc1 = reinterpret_cast<const float4*>(anchors)[a0 + TPB + tid];
    const float g0_tl0 = anc0.x - anc0.z * 0.5f, g0_tl1 = anc0.y - anc0.w * 0.5f;
    const float g0_br0 = anc0.x + anc0.z * 0.5f, g0_br1 = anc0.y + anc0.w * 0.5f;
    const float g0_ae  = anc0.z * anc0.w + 1e-8f;
    const float g1_tl0 = anc1.x - anc1.z * 0.5f, g1_tl1 = anc1.y - anc1.w * 0.5f;
    const float g1_br0 = anc1.x + anc1.z * 0.5f, g1_br1 = anc1.y + anc1.w * 0.5f;
    const float g1_ae  = anc1.z * anc1.w + 1e-8f;

    // ---- block bbox over both tiles (OOB lanes neutral) ----
    float m0 =  1e30f, m1 =  1e30f, M0 = -1e30f, M1 = -1e30f;
    if (in0) {
        m0 = g0_tl0; m1 = g0_tl1; M0 = g0_br0; M1 = g0_br1;
    }
    if (in1) {
        m0 = fminf(m0, g1_tl0); m1 = fminf(m1, g1_tl1);
        M0 = fmaxf(M0, g1_br0); M1 = fmaxf(M1, g1_br1);
    }
    #pragma unroll
    for (int off = 32; off; off >>= 1) {
        m0 = fminf(m0, __shfl_down(m0, off));
        m1 = fminf(m1, __shfl_down(m1, off));
        M0 = fmaxf(M0, __shfl_down(M0, off));
        M1 = fmaxf(M1, __shfl_down(M1, off));
    }
    __shared__ float s_red[4][NW];
    if (lane == 0) {
        s_red[0][wid] = m0; s_red[1][wid] = m1;
        s_red[2][wid] = M0; s_red[3][wid] = M1;
    }
    __syncthreads();

    // ---- wave 0 prunes + compacts targets ----
    __shared__ int s_act[MAXT];
    __shared__ int s_nact;
    if (wid == 0) {
        float bm0 = s_red[0][0], bm1 = s_red[1][0];
        float bM0 = s_red[2][0], bM1 = s_red[3][0];
        #pragma unroll
        for (int w = 1; w < NW; ++w) {
            bm0 = fminf(bm0, s_red[0][w]); bm1 = fminf(bm1, s_red[1][w]);
            bM0 = fmaxf(bM0, s_red[2][w]); bM1 = fmaxf(bM1, s_red[3][w]);
        }
        bool act = false;
        if (lane < T && T <= 64) {
            const float4 ta = s_ta[lane];
            act = (ta.x <= bM0) && (ta.y <= bM1) && (ta.z >= bm0) && (ta.w >= bm1);
        }
        const unsigned long long ball = __ballot(act);
        if (act) {
            const unsigned long long lm =
                (lane == 63) ? ~0ULL >> 1 : (1ULL << lane) - 1;
            s_act[__popcll(ball & lm)] = lane;
        }
        if (lane == 0) s_nact = __popcll(ball);
    }
    if (T > 64) {   // generic fallback: no pruning
        for (int i = tid; i < T; i += TPB) s_act[i] = i;
        if (tid == 0) s_nact = T;
    }
    __syncthreads();

    const int nact = s_nact;
    float raw = 0.f;
    float bI0 = -1.f, bU0 = 1.f; int bidx0 = 0;
    float bI1 = -1.f, bU1 = 1.f; int bidx1 = 0;

    // ---- two sequential tile passes (round-10 hot loop x2) ----
    if (C4T > 0 && nA == SPAN) {
        tile_pass<C4T>(tile, tid, nact, s_act, s_ta,
                       g0_tl0, g0_tl1, g0_br0, g0_br1, g0_ae,
                       raw, bI0, bU0, bidx0);
        tile_pass<C4T>(tile + (size_t)TPB * C4, tid, nact, s_act, s_ta,
                       g1_tl0, g1_tl1, g1_br0, g1_br1, g1_ae,
                       raw, bI1, bU1, bidx1);
    } else {
        // generic path (tail block / unexpected C)
        const int tot = nA * C4;
        for (int j = tid; j < tot; j += TPB)
            raw += f_bg4(tile[j]);
        for (int t = 0; t < nact; ++t) {
            const int tt = s_act[t];
            iou_step(g0_tl0, g0_tl1, g0_br0, g0_br1, g0_ae, s_ta[tt], tt,
                     bI0, bU0, bidx0);
            iou_step(g1_tl0, g1_tl1, g1_br0, g1_br1, g1_ae, s_ta[tt], tt,
                     bI1, bU1, bidx1);
        }
    }

    // ---- classify + smooth-L1 (scalar, per tile) ----
    const bool pos0 = in0 && (bI0 > 0.5f * bU0);
    const bool ign0 = in0 && !pos0 && !(bI0 < 0.4f * bU0);
    const bool pos1 = in1 && (bI1 > 0.5f * bU1);
    const bool ign1 = in1 && !pos1 && !(bI1 < 0.4f * bU1);
    int cls0 = 0, cls1 = 0;
    float sl1 = 0.f;

    if (pos0) {
        const float4 ta = s_ta[bidx0];
        cls0 = s_cls[bidx0];
        const float tz = ta.z - ta.x, tw = ta.w - ta.y;
        const float tx = (ta.x + ta.z) * 0.5f, ty = (ta.y + ta.w) * 0.5f;
        const float4 bp = reinterpret_cast<const float4*>(bbox_preds)[(size_t)b * A + a0 + tid];
        const float r0 = ((tx - anc0.x) / anc0.z) / 0.1f;
        const float r1 = ((ty - anc0.y) / anc0.w) / 0.1f;
        const float r2 = logf(tz / anc0.z + 1e-8f) / 0.2f;
        const float r3 = logf(tw / anc0.w + 1e-8f) / 0.2f;
        const float d0 = bp.x - r0, d1 = bp.y - r1, d2 = bp.z - r2, d3 = bp.w - r3;
        const float a0f = fabsf(d0), a1f = fabsf(d1), a2f = fabsf(d2), a3f = fabsf(d3);
        sl1 += (a0f < 1.f) ? 0.5f * d0 * d0 : a0f - 0.5f;
        sl1 += (a1f < 1.f) ? 0.5f * d1 * d1 : a1f - 0.5f;
        sl1 += (a2f < 1.f) ? 0.5f * d2 * d2 : a2f - 0.5f;
        sl1 += (a3f < 1.f) ? 0.5f * d3 * d3 : a3f - 0.5f;
    }
    if (pos1) {
        const float4 ta = s_ta[bidx1];
        cls1 = s_cls[bidx1];
        const float tz = ta.z - ta.x, tw = ta.w - ta.y;
        const float tx = (ta.x + ta.z) * 0.5f, ty = (ta.y + ta.w) * 0.5f;
        const float4 bp = reinterpret_cast<const float4*>(bbox_preds)[(size_t)b * A + a0 + TPB + tid];
        const float r0 = ((tx - anc1.x) / anc1.z) / 0.1f;
        const float r1 = ((ty - anc1.y) / anc1.w) / 0.1f;
        const float r2 = logf(tz / anc1.z + 1e-8f) / 0.2f;
        const float r3 = logf(tw / anc1.w + 1e-8f) / 0.2f;
        const float d0 = bp.x - r0, d1 = bp.y - r1, d2 = bp.z - r2, d3 = bp.w - r3;
        const float a0f = fabsf(d0), a1f = fabsf(d1), a2f = fabsf(d2), a3f = fabsf(d3);
        sl1 += (a0f < 1.f) ? 0.5f * d0 * d0 : a0f - 0.5f;
        sl1 += (a1f < 1.f) ? 0.5f * d1 * d1 : a1f - 0.5f;
        sl1 += (a2f < 1.f) ? 0.5f * d2 * d2 : a2f - 0.5f;
        sl1 += (a3f < 1.f) ? 0.5f * d3 * d3 : a3f - 0.5f;
    }

    // ---- merged deterministic compaction over 512 anchors ----
    const unsigned long long pb0 = __ballot(pos0), pb1 = __ballot(pos1);
    const unsigned long long ib0 = __ballot(ign0), ib1 = __ballot(ign1);

    __shared__ int s_pc[2][NW], s_ic[2][NW];
    __shared__ int s_plist[SPAN], s_pcls[SPAN], s_ilist[SPAN];
    if (lane == 0) {
        s_pc[0][wid] = __popcll(pb0); s_pc[1][wid] = __popcll(pb1);
        s_ic[0][wid] = __popcll(ib0); s_ic[1][wid] = __popcll(ib1);
    }
    __syncthreads();
    int p_total = 0, i_total = 0, t0p = 0, t0i = 0;
    #pragma unroll
    for (int w = 0; w < NW; ++w) {
        t0p += s_pc[0][w]; t0i += s_ic[0][w];
        p_total += s_pc[0][w] + s_pc[1][w];
        i_total += s_ic[0][w] + s_ic[1][w];
    }
    int p_off0 = 0, i_off0 = 0, p_off1 = t0p, i_off1 = t0i;
    #pragma unroll
    for (int w = 0; w < NW; ++w) {
        if (w < wid) {
            p_off0 += s_pc[0][w]; i_off0 += s_ic[0][w];
            p_off1 += s_pc[1][w]; i_off1 += s_ic[1][w];
        }
    }
    const unsigned long long lmask = (lane == 63) ? ~0ULL >> 1 : (1ULL << lane) - 1;
    if (pos0) {
        const int idx = p_off0 + __popcll(pb0 & lmask);
        s_plist[idx] = a0 + tid; s_pcls[idx] = cls0;
    }
    if (pos1) {
        const int idx = p_off1 + __popcll(pb1 & lmask);
        s_plist[idx] = a0 + TPB + tid; s_pcls[idx] = cls1;
    }
    if (ign0) s_ilist[i_off0 + __popcll(ib0 & lmask)] = a0 + tid;
    if (ign1) s_ilist[i_off1 + __popcll(ib1 & lmask)] = a0 + TPB + tid;
    __syncthreads();

    // ---- sparse corrections ----
    float corr = 0.f;
    for (int j = tid; j < p_total; j += TPB) {
        const int pa = s_plist[j];
        const int pc = s_pcls[j];
        corr += f_fg_minus_bg(clas_preds[((size_t)b * A + pa) * (C4 * 4) + (pc - 1)]);
    }
    const int ig_elems = i_total * C4;   // rare: usually 0
    for (int j = tid; j < ig_elems; j += TPB) {
        const int ii = j / C4;
        const int c4 = j - ii * C4;
        const int ia = s_ilist[ii];
        raw -= f_bg4(reinterpret_cast<const float4*>(clas_preds)
                         [((size_t)b * A + ia) * C4 + c4]);
    }

    // ---- block reduction -> one partial per 512 anchors ----
    float v = sl1;
    float u = fmaf(raw, K_BG, corr);
    #pragma unroll
    for (int off = 32; off; off >>= 1) {
        v += __shfl_down(v, off);
        u += __shfl_down(u, off);
    }
    __shared__ float s_sl1[NW], s_cl2[NW];
    if (lane == 0) { s_sl1[wid] = v; s_cl2[wid] = u; }
    __syncthreads();
    if (tid == 0) {
        float tv = 0.f, tu = 0.f;
        #pragma unroll
        for (int w = 0; w < NW; ++w) { tv += s_sl1[w]; tu += s_cl2[w]; }
        const size_t o = (size_t)b * nblk + blockIdx.x;
        bb_p[o] = tv;
        cl_p[o] = tu;
        np_p[o] = (float)p_total;
    }
}

// ---------------------------------------------------------------------------
// Final reduce: one wave per image, thread 0 emits the scalar.
// ---------------------------------------------------------------------------
__global__ void reduce_kernel(const float* __restrict__ np_p,  // [B*nblk]
                              const float* __restrict__ bb_p,
                              const float* __restrict__ cl_p,
                              int nblk, int Bn,
                              float* __restrict__ out)
{
    const int wid  = threadIdx.x >> 6;
    const int lane = threadIdx.x & 63;
    const int nw   = blockDim.x >> 6;
    __shared__ float s_loss[32];

    float acc = 0.f;
    for (int b = wid; b < Bn; b += nw) {
        float cl = 0.f, bb = 0.f, np = 0.f;
        for (int i = lane; i < nblk; i += 64) {
            const size_t o = (size_t)b * nblk + i;
            np += np_p[o]; bb += bb_p[o]; cl += cl_p[o];
        }
        #pragma unroll
        for (int off = 32; off; off >>= 1) {
            cl += __shfl_down(cl, off);
            bb += __shfl_down(bb, off);
            np += __shfl_down(np, off);
        }
        if (lane == 0)
            acc += bb / fmaxf(4.f * np, 1.f) + cl / fmaxf(np, 1.f);
    }
    if (lane == 0) s_loss[wid] = acc;
    __syncthreads();
    if (threadIdx.x == 0) {
        float v = 0.f;
        for (int w = 0; w < nw; ++w) v += s_loss[w];
        out[0] = v / (float)Bn;
    }
}

// ---------------------------------------------------------------------------
extern "C" void kernel_launch(void* const* d_in, const int* in_sizes, int n_in,
                              void* d_out, int out_size, void* d_ws, size_t ws_size,
                              hipStream_t stream)
{
    const float* clas_preds = (const float*)d_in[0];
    const float* bbox_preds = (const float*)d_in[1];
    const float* bbox_tgts  = (const float*)d_in[2];
    const int*   clas_tgts  = (const int*)d_in[3];
    const float* anchors    = (const float*)d_in[4];

    const int A  = in_sizes[4] / 4;
    const int Bn = in_sizes[1] / (A * 4);
    const int T  = in_sizes[3] / Bn;
    const int C  = in_sizes[0] / (Bn * A);
    const int C4 = C / 4;

    const int nblk = (A + SPAN - 1) / SPAN;

    // workspace: np_p | bb_p | cl_p, each float[B*nblk]
    char* ws = (char*)d_ws;
    float* np_p = (float*)ws;  ws += (size_t)Bn * nblk * sizeof(float);
    float* bb_p = (float*)ws;  ws += (size_t)Bn * nblk * sizeof(float);
    float* cl_p = (float*)ws;

    dim3 g1((unsigned)nblk, (unsigned)Bn);
    if (C4 == 20) {
        fused_kernel<20><<<g1, TPB, 0, stream>>>(
            bbox_preds, bbox_tgts, clas_tgts, anchors, clas_preds,
            A, T, C4, np_p, bb_p, cl_p, nblk);
    } else {
        fused_kernel<0><<<g1, TPB, 0, stream>>>(
            bbox_preds, bbox_tgts, clas_tgts, anchors, clas_preds,
            A, T, C4, np_p, bb_p, cl_p, nblk);
    }

    reduce_kernel<<<1, 1024, 0, stream>>>(np_p, bb_p, cl_p, nblk, Bn, (float*)d_out);
}

// Round 13
// 61.994 us; speedup vs baseline: 1.8770x; 1.8770x over previous
//
#include <hip/hip_runtime.h>
#include <cstdint>
#include <cstddef>

#define TPB 256
#define MAXT 128   // max targets supported (T=64 here)
#define BIGC 1e18f // far-away point box for invalid targets (area 0, no overlap)

// ---------------------------------------------------------------------------
// Focal-term helpers.
// f_bg(x)  = 0.25 * sigmoid(x)^2 * softplus(x)        (background / enc=0)
// f_fg(x)  = 0.75 * (1-sigmoid(x))^2 * softplus(-x)   (target / enc=1)
// f_bg4 returns RAW sum sigmoid^2 * softplus(x)/ln2; caller multiplies by
// K_BG = 0.25*ln2 once at the end.  ~7 VALU + 3 hw-trans per element.
// ---------------------------------------------------------------------------
#define K_BG 0.17328679514f   // 0.25 * ln(2)

__device__ __forceinline__ float f_bg4(float4 v) {
    float r = 0.f;
    const float xs[4] = {v.x, v.y, v.z, v.w};
    #pragma unroll
    for (int i = 0; i < 4; ++i) {
        const float x  = xs[i];
        const float u  = x * 1.44269504089f;                 // x * log2(e)
        const float em = __builtin_amdgcn_exp2f(-fabsf(u));  // e^-|x| (src mods)
        const float oe = 1.f + em;
        const float l2 = __builtin_amdgcn_logf(oe);          // log2(1+e^-|x|)
        const float s  = __builtin_amdgcn_rcpf(oe);          // sigmoid(|x|)
        const float sp2 = fmaxf(u, 0.f) + l2;                // softplus(x)/ln2
        const float p  = (x >= 0.f) ? s : (1.f - s);         // sigmoid(x)
        r = fmaf(p * p, sp2, r);
    }
    return r;
}

__device__ __forceinline__ float f_fg_minus_bg(float x) {
    const float ax = fabsf(x);
    const float em = __builtin_amdgcn_exp2f(ax * -1.44269504089f);
    const float oe = 1.f + em;
    const float l  = __builtin_amdgcn_logf(oe) * 0.69314718056f;
    const float s  = __builtin_amdgcn_rcpf(oe);
    const float sp_p = (x >= 0.f) ? (x + l) : l;   // softplus(x)
    const float sp_n = sp_p - x;                   // softplus(-x)
    const float p  = (x >= 0.f) ? s : (1.f - s);
    const float q  = 1.f - p;
    return 0.75f * q * q * sp_n - 0.25f * p * p * sp_p;
}

// ---------------------------------------------------------------------------
// Fused kernel. Per block = 256 contiguous anchors of one image.
//   0a: issue first 5 focal float4 loads (independent of LDS)
//   0b: stage 64 targets -> LDS; block anchor-bbox reduce
//   0c: wave 0 prunes targets vs block bbox -> compacted active list
//       (pruned target => IoU==0 for EVERY anchor in block => classifications
//        identical; best stays sentinel/0 < 0.4 => background)
//   1 : interleaved {prefetch 5 | f_bg x20 | IoU over active-list chunk}
//       cross-multiplied argmax (no per-target rcp), 1 b128 LDS read/target
//   2 : pos/ign via multiply-compare thresholds; smooth-L1 for positives
//   3 : ballot compaction, sparse corrections, block reduce -> partials.
// __launch_bounds__(256,4): VGPR cap 128 -> >=16 waves/CU.  No atomics.
// ---------------------------------------------------------------------------
template<int C4T>
__global__ __launch_bounds__(TPB, 4)
void fused_kernel(const float* __restrict__ bbox_preds,  // [B,A,4]
                  const float* __restrict__ bbox_tgts,   // [B,T,4] tlbr
                  const int*   __restrict__ clas_tgts,   // [B,T]
                  const float* __restrict__ anchors,     // [A,4] cthw
                  const float* __restrict__ clas_preds,  // [B,A,C]
                  int A, int T, int C4rt,
                  float* __restrict__ np_p,   // [B*nblk]
                  float* __restrict__ bb_p,   // [B*nblk]
                  float* __restrict__ cl_p,   // [B*nblk]
                  int nblk)
{
    const int C4  = (C4T > 0) ? C4T : C4rt;
    const int b   = blockIdx.y;
    const int a0  = blockIdx.x * TPB;
    const int tid = threadIdx.x;
    const int a   = a0 + tid;
    const bool in = (a < A);
    const int lane = tid & 63;
    const int wid  = tid >> 6;

    const int nA = min(TPB, A - a0);
    const float4* tile = reinterpret_cast<const float4*>(clas_preds)
                         + ((size_t)b * A + a0) * C4;

    // ---- 0a: issue first focal loads ASAP (hide under staging) ----
    constexpr int CH  = 5;
    constexpr int NCH = (C4T > 0 ? C4T : 5) / CH;   // 4 for C4=20
    float4 cur[CH];
    if (C4T > 0 && nA == TPB) {
        #pragma unroll
        for (int i = 0; i < CH; ++i) cur[i] = tile[tid + i * TPB];
    }

    // ---- 0b: stage targets; block anchor bbox ----
    __shared__ float4 s_ta[MAXT];   // tlbr (point box at BIGC if invalid)
    __shared__ float4 s_tb[MAXT];   // c0,c1,s0,s1 (for smooth-L1, rare)
    __shared__ int    s_cls[MAXT];
    for (int i = tid; i < T; i += TPB) {
        const float4 tg = reinterpret_cast<const float4*>(bbox_tgts)[(size_t)b * T + i];
        const int   cl = clas_tgts[(size_t)b * T + i];
        const float c0 = (tg.x + tg.z) * 0.5f, c1 = (tg.y + tg.w) * 0.5f;
        const float s0 = tg.z - tg.x,          s1 = tg.w - tg.y;
        const bool  val = (cl > 0);
        s_ta[i] = val ? make_float4(c0 - s0 * 0.5f, c1 - s1 * 0.5f,
                                    c0 + s0 * 0.5f, c1 + s1 * 0.5f)
                      : make_float4(BIGC, BIGC, BIGC, BIGC);
        s_tb[i] = make_float4(c0, c1, s0, s1);
        s_cls[i] = cl;
    }

    float4 anc = make_float4(0.f, 0.f, 1.f, 1.f);
    if (in) anc = reinterpret_cast<const float4*>(anchors)[a];
    const float a_tl0 = anc.x - anc.z * 0.5f;
    const float a_tl1 = anc.y - anc.w * 0.5f;
    const float a_br0 = anc.x + anc.z * 0.5f;
    const float a_br1 = anc.y + anc.w * 0.5f;
    const float a_area_eps = anc.z * anc.w + 1e-8f;

    // block bbox reduce (OOB lanes neutral)
    float m0 = in ? a_tl0 :  1e30f, m1 = in ? a_tl1 :  1e30f;
    float M0 = in ? a_br0 : -1e30f, M1 = in ? a_br1 : -1e30f;
    #pragma unroll
    for (int off = 32; off; off >>= 1) {
        m0 = fminf(m0, __shfl_down(m0, off));
        m1 = fminf(m1, __shfl_down(m1, off));
        M0 = fmaxf(M0, __shfl_down(M0, off));
        M1 = fmaxf(M1, __shfl_down(M1, off));
    }
    __shared__ float s_red[4][TPB / 64];
    if (lane == 0) {
        s_red[0][wid] = m0; s_red[1][wid] = m1;
        s_red[2][wid] = M0; s_red[3][wid] = M1;
    }
    __syncthreads();

    // ---- 0c: wave 0 prunes + compacts targets ----
    __shared__ int s_act[MAXT];
    __shared__ int s_nact;
    if (wid == 0) {
        float bm0 = s_red[0][0], bm1 = s_red[1][0];
        float bM0 = s_red[2][0], bM1 = s_red[3][0];
        #pragma unroll
        for (int w = 1; w < TPB / 64; ++w) {
            bm0 = fminf(bm0, s_red[0][w]); bm1 = fminf(bm1, s_red[1][w]);
            bM0 = fmaxf(bM0, s_red[2][w]); bM1 = fmaxf(bM1, s_red[3][w]);
        }
        bool act = false;
        if (lane < T && T <= 64) {
            const float4 ta = s_ta[lane];
            act = (ta.x <= bM0) && (ta.y <= bM1) && (ta.z >= bm0) && (ta.w >= bm1);
        }
        const unsigned long long ball = __ballot(act);
        if (act) {
            const unsigned long long lm =
                (lane == 63) ? ~0ULL >> 1 : (1ULL << lane) - 1;
            s_act[__popcll(ball & lm)] = lane;
        }
        if (lane == 0) s_nact = __popcll(ball);
    }
    if (T > 64) {   // generic fallback: no pruning
        for (int i = tid; i < T; i += TPB) s_act[i] = i;
        if (tid == 0) s_nact = T;
    }
    __syncthreads();

    const int nact = s_nact;
    float bI = -1.f, bU = 1.f;   // sentinel: iou = -1
    int   besti = 0;

#define IOU_STEP(tt)                                                        \
    {                                                                       \
        const float4 ta = s_ta[tt];                                         \
        const float tl0 = fmaxf(a_tl0, ta.x);                               \
        const float tl1 = fmaxf(a_tl1, ta.y);                               \
        const float br0 = fminf(a_br0, ta.z);                               \
        const float br1 = fminf(a_br1, ta.w);                               \
        const float sz0 = fmaxf(br0 - tl0, 0.0f);                           \
        const float sz1 = fmaxf(br1 - tl1, 0.0f);                           \
        const float inter = sz0 * sz1;                                      \
        const float tarea = (ta.z - ta.x) * (ta.w - ta.y);                  \
        const float uni = a_area_eps + tarea - inter;                       \
        const bool upd = inter * bU > bI * uni;  /* iou_t > iou_best */     \
        bI = upd ? inter : bI;                                              \
        bU = upd ? uni   : bU;                                              \
        besti = upd ? (tt) : besti;                                         \
    }

    float raw = 0.f;
    if (C4T > 0 && nA == TPB) {
        const int cs = (nact + NCH - 1) / NCH;   // active-list chunk per group
        #pragma unroll
        for (int g = 0; g < NCH; ++g) {
            float4 nxt[CH];
            if (g + 1 < NCH) {
                #pragma unroll
                for (int i = 0; i < CH; ++i)
                    nxt[i] = tile[tid + ((g + 1) * CH + i) * TPB];
            }
            #pragma unroll
            for (int i = 0; i < CH; ++i) raw += f_bg4(cur[i]);
            const int te = min((g + 1) * cs, nact);
            for (int t = g * cs; t < te; ++t) IOU_STEP(s_act[t])
            if (g + 1 < NCH) {
                #pragma unroll
                for (int i = 0; i < CH; ++i) cur[i] = nxt[i];
            }
        }
    } else {
        // generic path (tail blocks / unexpected C)
        const int tot = nA * C4;
        for (int j = tid; j < tot; j += TPB)
            raw += f_bg4(tile[j]);
        for (int t = 0; t < nact; ++t) IOU_STEP(s_act[t])
    }
#undef IOU_STEP

    // ---- phase 2: classify (multiply-compare) + smooth-L1 ----
    const bool pos = in && (bI > 0.5f * bU);
    const bool ign = in && !pos && !(bI < 0.4f * bU);   // 0.4 <= iou <= 0.5

    float sl1 = 0.f;
    int   cls = 0;
    if (pos) {
        // rare path: precise logf + divs, negligible
        const float4 tb = s_tb[besti];
        cls = s_cls[besti];
        const float4 bp = reinterpret_cast<const float4*>(bbox_preds)[(size_t)b * A + a];
        const float tc0 = (tb.x - anc.x) / anc.z;
        const float tc1 = (tb.y - anc.y) / anc.w;
        const float ts0 = logf(tb.z / anc.z + 1e-8f);
        const float ts1 = logf(tb.w / anc.w + 1e-8f);
        const float r0 = tc0 / 0.1f, r1 = tc1 / 0.1f;
        const float r2 = ts0 / 0.2f, r3 = ts1 / 0.2f;
        const float d0 = bp.x - r0, d1 = bp.y - r1, d2 = bp.z - r2, d3 = bp.w - r3;
        const float a0f = fabsf(d0), a1f = fabsf(d1), a2f = fabsf(d2), a3f = fabsf(d3);
        sl1 += (a0f < 1.f) ? 0.5f * d0 * d0 : a0f - 0.5f;
        sl1 += (a1f < 1.f) ? 0.5f * d1 * d1 : a1f - 0.5f;
        sl1 += (a2f < 1.f) ? 0.5f * d2 * d2 : a2f - 0.5f;
        sl1 += (a3f < 1.f) ? 0.5f * d3 * d3 : a3f - 0.5f;
    }

    // ---- phase 3: deterministic ballot compaction ----
    const unsigned long long pball = __ballot(pos);
    const unsigned long long iball = __ballot(ign);

    __shared__ int s_pc[TPB / 64], s_ic[TPB / 64];
    __shared__ int s_plist[TPB], s_pcls[TPB], s_ilist[TPB];
    if (lane == 0) { s_pc[wid] = __popcll(pball); s_ic[wid] = __popcll(iball); }
    __syncthreads();
    int p_off = 0, i_off = 0, p_total = 0, i_total = 0;
    #pragma unroll
    for (int w = 0; w < TPB / 64; ++w) {
        if (w < wid) { p_off += s_pc[w]; i_off += s_ic[w]; }
        p_total += s_pc[w]; i_total += s_ic[w];
    }
    const unsigned long long lmask = (lane == 63) ? ~0ULL >> 1 : (1ULL << lane) - 1;
    if (pos) {
        const int idx = p_off + __popcll(pball & lmask);
        s_plist[idx] = a; s_pcls[idx] = cls;
    }
    if (ign) {
        const int idx = i_off + __popcll(iball & lmask);
        s_ilist[idx] = a;
    }
    __syncthreads();

    // ---- phase 4: sparse corrections ----
    float corr = 0.f;
    if (tid < p_total) {
        const int pa = s_plist[tid];
        const int pc = s_pcls[tid];
        const float x = clas_preds[((size_t)b * A + pa) * (C4 * 4) + (pc - 1)];
        corr += f_fg_minus_bg(x);
    }
    const int ig_elems = i_total * C4;   // rare: usually 0
    for (int j = tid; j < ig_elems; j += TPB) {
        const int ii = j / C4;
        const int c4 = j - ii * C4;
        const int ia = s_ilist[ii];
        raw -= f_bg4(reinterpret_cast<const float4*>(clas_preds)
                         [((size_t)b * A + ia) * C4 + c4]);
    }

    // ---- phase 5: block reduction -> partials ----
    float v = sl1;
    float u = fmaf(raw, K_BG, corr);
    #pragma unroll
    for (int off = 32; off; off >>= 1) {
        v += __shfl_down(v, off);
        u += __shfl_down(u, off);
    }
    __shared__ float s_sl1[TPB / 64], s_cl[TPB / 64];
    if (lane == 0) { s_sl1[wid] = v; s_cl[wid] = u; }
    __syncthreads();
    if (tid == 0) {
        float tv = 0.f, tu = 0.f;
        #pragma unroll
        for (int w = 0; w < TPB / 64; ++w) { tv += s_sl1[w]; tu += s_cl[w]; }
        const size_t o = (size_t)b * nblk + blockIdx.x;
        bb_p[o] = tv;
        cl_p[o] = tu;
        np_p[o] = (float)p_total;
    }
}

// ---------------------------------------------------------------------------
// Final reduce: one wave per image, thread 0 emits the scalar.
// ---------------------------------------------------------------------------
__global__ void reduce_kernel(const float* __restrict__ np_p,  // [B*nblk]
                              const float* __restrict__ bb_p,
                              const float* __restrict__ cl_p,
                              int nblk, int Bn,
                              float* __restrict__ out)
{
    const int wid  = threadIdx.x >> 6;
    const int lane = threadIdx.x & 63;
    const int nw   = blockDim.x >> 6;
    __shared__ float s_loss[32];

    float acc = 0.f;
    for (int b = wid; b < Bn; b += nw) {
        float cl = 0.f, bb = 0.f, np = 0.f;
        for (int i = lane; i < nblk; i += 64) {
            const size_t o = (size_t)b * nblk + i;
            np += np_p[o]; bb += bb_p[o]; cl += cl_p[o];
        }
        #pragma unroll
        for (int off = 32; off; off >>= 1) {
            cl += __shfl_down(cl, off);
            bb += __shfl_down(bb, off);
            np += __shfl_down(np, off);
        }
        if (lane == 0)
            acc += bb / fmaxf(4.f * np, 1.f) + cl / fmaxf(np, 1.f);
    }
    if (lane == 0) s_loss[wid] = acc;
    __syncthreads();
    if (threadIdx.x == 0) {
        float v = 0.f;
        for (int w = 0; w < nw; ++w) v += s_loss[w];
        out[0] = v / (float)Bn;
    }
}

// ---------------------------------------------------------------------------
extern "C" void kernel_launch(void* const* d_in, const int* in_sizes, int n_in,
                              void* d_out, int out_size, void* d_ws, size_t ws_size,
                              hipStream_t stream)
{
    const float* clas_preds = (const float*)d_in[0];
    const float* bbox_preds = (const float*)d_in[1];
    const float* bbox_tgts  = (const float*)d_in[2];
    const int*   clas_tgts  = (const int*)d_in[3];
    const float* anchors    = (const float*)d_in[4];

    const int A  = in_sizes[4] / 4;
    const int Bn = in_sizes[1] / (A * 4);
    const int T  = in_sizes[3] / Bn;
    const int C  = in_sizes[0] / (Bn * A);
    const int C4 = C / 4;

    const int nblk = (A + TPB - 1) / TPB;

    // workspace: np_p | bb_p | cl_p, each float[B*nblk]
    char* ws = (char*)d_ws;
    float* np_p = (float*)ws;  ws += (size_t)Bn * nblk * sizeof(float);
    float* bb_p = (float*)ws;  ws += (size_t)Bn * nblk * sizeof(float);
    float* cl_p = (float*)ws;

    dim3 g1((unsigned)nblk, (unsigned)Bn);
    if (C4 == 20) {
        fused_kernel<20><<<g1, TPB, 0, stream>>>(
            bbox_preds, bbox_tgts, clas_tgts, anchors, clas_preds,
            A, T, C4, np_p, bb_p, cl_p, nblk);
    } else {
        fused_kernel<0><<<g1, TPB, 0, stream>>>(
            bbox_preds, bbox_tgts, clas_tgts, anchors, clas_preds,
            A, T, C4, np_p, bb_p, cl_p, nblk);
    }

    reduce_kernel<<<1, 1024, 0, stream>>>(np_p, bb_p, cl_p, nblk, Bn, (float*)d_out);
}